// Round 14
// baseline (674.219 us; speedup 1.0000x reference)
//
#include <hip/hip_runtime.h>
#include <hip/hip_bf16.h>
#include <hip/hip_cooperative_groups.h>
#include <stdint.h>

namespace cg = cooperative_groups;

typedef unsigned int u32;
typedef unsigned long long u64;

#define K_SEL 512
#define NBINS 4096
#define CAP 8192
#define SCORE_THR 0.05f
#define NMS_THR 0.5f
#define RPB 3072
#define SLABS 128

__device__ __forceinline__ u32 fkey(float x) {
  u32 u = __float_as_uint(x);
  return u ^ ((u32)((int)u >> 31) | 0x80000000u);
}
__device__ __forceinline__ float fkey_inv(u32 k) {
  u32 u = (k & 0x80000000u) ? (k ^ 0x80000000u) : ~k;
  return __uint_as_float(u);
}

struct MegaArgs {
  const float* logits;
  const float* deltas;
  const float* anchors;
  float* out;
  u32* skey;
  u32* histp;
  u32* hred;
  u32* cutT;
  u64* cand;
  u32* cnt;
  float* corners;
  float4* meta;
  u64* validw;
  u64* sup;
  float4* zbuf;
  int nz4, N, C, off_scores, off_labels, off_keep;
};

// NMS sweep macros (single-word chain + catch-up ORs), as in R13.
#define NSTEP(PB, S, cc)                                                   \
  {                                                                        \
    u64 live_ = ((vv >> (S)) & ~(rw >> (S))) & 1ull;                       \
    u64 m_ = (u64)0 - live_;                                               \
    rw |= PB & m_;                                                         \
    km |= live_ << (S);                                                    \
    if ((S) < 48) PB = lsn[((cc)*64 + (S) + 16) * 8 + (cc)];               \
  }

#define NGROUP16(S0, cc)                                                   \
  NSTEP(P0, (S0) + 0, cc) NSTEP(P1, (S0) + 1, cc)                          \
  NSTEP(P2, (S0) + 2, cc) NSTEP(P3, (S0) + 3, cc)                          \
  NSTEP(P4, (S0) + 4, cc) NSTEP(P5, (S0) + 5, cc)                          \
  NSTEP(P6, (S0) + 6, cc) NSTEP(P7, (S0) + 7, cc)                          \
  NSTEP(P8, (S0) + 8, cc) NSTEP(P9, (S0) + 9, cc)                          \
  NSTEP(P10, (S0) + 10, cc) NSTEP(P11, (S0) + 11, cc)                      \
  NSTEP(P12, (S0) + 12, cc) NSTEP(P13, (S0) + 13, cc)                      \
  NSTEP(P14, (S0) + 14, cc) NSTEP(P15, (S0) + 15, cc)

#define NCHUNK(cc)                                                         \
  {                                                                        \
    u64 vv = vsh[cc];                                                      \
    u64 rw = rem[cc];                                                      \
    u64 km = 0;                                                            \
    u64 P0 = lsn[((cc)*64 + 0) * 8 + (cc)];                                \
    u64 P1 = lsn[((cc)*64 + 1) * 8 + (cc)];                                \
    u64 P2 = lsn[((cc)*64 + 2) * 8 + (cc)];                                \
    u64 P3 = lsn[((cc)*64 + 3) * 8 + (cc)];                                \
    u64 P4 = lsn[((cc)*64 + 4) * 8 + (cc)];                                \
    u64 P5 = lsn[((cc)*64 + 5) * 8 + (cc)];                                \
    u64 P6 = lsn[((cc)*64 + 6) * 8 + (cc)];                                \
    u64 P7 = lsn[((cc)*64 + 7) * 8 + (cc)];                                \
    u64 P8 = lsn[((cc)*64 + 8) * 8 + (cc)];                                \
    u64 P9 = lsn[((cc)*64 + 9) * 8 + (cc)];                                \
    u64 P10 = lsn[((cc)*64 + 10) * 8 + (cc)];                              \
    u64 P11 = lsn[((cc)*64 + 11) * 8 + (cc)];                              \
    u64 P12 = lsn[((cc)*64 + 12) * 8 + (cc)];                              \
    u64 P13 = lsn[((cc)*64 + 13) * 8 + (cc)];                              \
    u64 P14 = lsn[((cc)*64 + 14) * 8 + (cc)];                              \
    u64 P15 = lsn[((cc)*64 + 15) * 8 + (cc)];                              \
    NGROUP16(0, cc) NGROUP16(16, cc) NGROUP16(32, cc) NGROUP16(48, cc)     \
    u64 kk = km;                                                           \
    while (kk) {                                                           \
      int r_ = (cc)*64 + __builtin_ctzll(kk);                              \
      kk &= kk - 1ull;                                                     \
      const u64* rb_ = lsn + r_ * 8;                                       \
      rem[0] |= rb_[0]; rem[1] |= rb_[1]; rem[2] |= rb_[2];                \
      rem[3] |= rb_[3]; rem[4] |= rb_[4]; rem[5] |= rb_[5];                \
      rem[6] |= rb_[6]; rem[7] |= rb_[7];                                  \
    }                                                                      \
    ko[(cc)*64 + lane] = (float)((km >> lane) & 1ull);                     \
  }

__global__ __launch_bounds__(256, 2) void k_mega(MegaArgs a) {
  cg::grid_group grid = cg::this_grid();
  __shared__ __align__(16) char smem[33024];
  const int bid = blockIdx.x;
  const int tid = threadIdx.x;
  const int B = (int)gridDim.x >> 7;  // grid = B * SLABS
  const int N = a.N;

  // ---------- P1: zero ws + fused max+hist (private slab flush) ----------
  {
    for (int i = bid * 256 + tid; i < a.nz4; i += gridDim.x * 256)
      a.zbuf[i] = make_float4(0.f, 0.f, 0.f, 0.f);
    float* tile = (float*)smem;               // 15360 B
    u32* sh = (u32*)(smem + 15360);           // 16384 B
    int b = bid >> 7, lb = bid & (SLABS - 1);
    for (int i = tid; i < NBINS; i += 256) sh[i] = 0;
    int r0 = lb * RPB;
    for (int c = 0; c < RPB / 256; c++) {
      int n0 = r0 + c * 256;
      if (n0 >= N) break;
      int nrow = min(256, N - n0);
      const float* src = a.logits + ((size_t)b * N + n0) * 15;
      int tot = nrow * 15;
      if (((tot & 3) == 0) && ((((size_t)src) & 15) == 0)) {
        const float4* s4 = (const float4*)src;
        float4* t4 = (float4*)tile;
        int n4 = tot >> 2;
        for (int i = tid; i < n4; i += 256) t4[i] = s4[i];
      } else {
        for (int i = tid; i < tot; i += 256) tile[i] = src[i];
      }
      __syncthreads();
      if (tid < nrow) {
        const float* row = tile + tid * 15;
        float mv = row[0];
        for (int cc = 1; cc < 15; cc++) mv = fmaxf(mv, row[cc]);
        u32 key = fkey(mv);
        a.skey[(size_t)b * N + n0 + tid] = key;
        atomicAdd(&sh[key >> 20], 1u);
      }
      __syncthreads();
    }
    u32* hp = a.histp + (size_t)bid * NBINS;
    for (int i = tid; i < NBINS; i += 256) hp[i] = sh[i];
  }
  __threadfence();
  grid.sync();

  // ---------- P2: wide slab reduction ----------
  if (bid < B * (NBINS / 256)) {
    int b = bid >> 4;
    int bin = (bid & 15) * 256 + tid;
    const u32* base = a.histp + (size_t)b * SLABS * NBINS + bin;
    u32 s = 0;
#pragma unroll 8
    for (int sl = 0; sl < SLABS; sl++) s += base[(size_t)sl * NBINS];
    a.hred[b * NBINS + bin] = s;
  }
  __threadfence();
  grid.sync();

  // ---------- P3: cutoff ----------
  if (bid < B) {
    int b = bid;
    const u32* hb = a.hred + b * NBINS;
    u32 h[16];
    u32 s = 0;
#pragma unroll
    for (int i = 0; i < 16; i++) {
      h[i] = hb[tid * 16 + i];
      s += h[i];
    }
    u32* cs = (u32*)smem;
    cs[tid] = s;
    __syncthreads();
    for (int off = 1; off < 256; off <<= 1) {
      u32 add = (tid + off < 256) ? cs[tid + off] : 0;
      __syncthreads();
      cs[tid] += add;
      __syncthreads();
    }
    u32 run = (tid < 255) ? cs[tid + 1] : 0;
    for (int i = 15; i >= 0; i--) {
      u32 sfx = run + h[i];
      if (run < (u32)K_SEL && sfx >= (u32)K_SEL)
        a.cutT[b] = (u32)(tid * 16 + i);
      run = sfx;
    }
  }
  __threadfence();
  grid.sync();

  // ---------- P4: compact (grid-stride over virtual blocks) ----------
  {
    volatile u32* lcnt = (volatile u32*)smem;
    volatile u32* lbase = ((volatile u32*)smem) + 1;
    int NB = (N + 255) >> 8;
    for (int vb = bid; vb < NB * B; vb += gridDim.x) {
      int b = vb / NB;
      int n = (vb - b * NB) * 256 + tid;
      if (tid == 0) *lcnt = 0;
      __syncthreads();
      u32 key = 0;
      bool ok = false;
      u32 lpos = 0;
      if (n < N) {
        key = a.skey[(size_t)b * N + n];
        ok = (key >> 20) >= a.cutT[b];
      }
      if (ok) lpos = atomicAdd((u32*)lcnt, 1u);
      __syncthreads();
      if (tid == 0 && *lcnt) *lbase = atomicAdd(&a.cnt[b * 32], *lcnt);
      __syncthreads();
      if (ok) {
        u32 pos = *lbase + lpos;
        if (pos < CAP)
          a.cand[(size_t)b * CAP + pos] = ((u64)key << 32) | (u32)(~(u32)n);
      }
      __syncthreads();
    }
  }
  __threadfence();
  grid.sync();

  // ---------- P5: rank by counting + decode ----------
  {
    u64* t = (u64*)smem;  // 2048 B
    if (bid < 32 * B) {
      int b = bid >> 5, bx = bid & 31;
      int M = (int)min(a.cnt[b * 32], (u32)CAP);
      if (bx * 256 < M) {
        int m = bx * 256 + tid;
        u64 my = (m < M) ? a.cand[(size_t)b * CAP + m] : 0ull;
        int rank = 0;
        for (int j0 = 0; j0 < M; j0 += 256) {
          int j = j0 + tid;
          t[tid] = (j < M) ? a.cand[(size_t)b * CAP + j] : 0ull;
          __syncthreads();
          int lim = min(256, M - j0);
          for (int jj = 0; jj < lim; jj++) rank += (t[jj] > my) ? 1 : 0;
          __syncthreads();
        }
        if (m < M && rank < K_SEL) {
          int g = b * K_SEL + rank;
          u32 key = (u32)(my >> 32);
          int idx = (int)(~(u32)my);
          float ml = fkey_inv(key);
          float score = 1.0f / (1.0f + expf(-ml));
          const float* lr = a.logits + ((size_t)b * N + idx) * a.C;
          float bv = lr[0];
          int lab = 0;
          for (int c = 1; c < a.C; c++) {
            float v = lr[c];
            if (v > bv) { bv = v; lab = c; }
          }
          const float* ar = a.anchors + (size_t)idx * 5;
          const float* dr = a.deltas + ((size_t)b * N + idx) * 5;
          float ax = ar[0], ay = ar[1], aw = ar[2], ah = ar[3], aa = ar[4];
          float dx = dr[0], dy = dr[1], dwv = dr[2], dhv = dr[3],
                da = dr[4];
          float px = ax + dx * aw;
          float py = ay + dy * ah;
          float pw = aw * expf(fminf(fmaxf(dwv, -4.0f), 4.0f));
          float ph = ah * expf(fminf(fmaxf(dhv, -4.0f), 4.0f));
          float pa = aa + da * 57.295779513082323f;
          float* ob = a.out + (size_t)g * 5;
          ob[0] = px; ob[1] = py; ob[2] = pw; ob[3] = ph; ob[4] = pa;
          a.out[a.off_scores + g] = score;
          a.out[a.off_labels + g] = (float)lab;
          if (score > SCORE_THR)
            atomicOr(&a.validw[g >> 6], 1ull << (g & 63));
          float tt = pa * 0.017453292519943295f;
          float cc = cosf(tt), sn = sinf(tt);
          float hx = pw * 0.5f, hy = ph * 0.5f;
          float* cp = a.corners + (size_t)g * 8;
          cp[0] = px + cc * (-hx) - sn * (-hy);
          cp[1] = py + sn * (-hx) + cc * (-hy);
          cp[2] = px + cc * (hx) - sn * (-hy);
          cp[3] = py + sn * (hx) + cc * (-hy);
          cp[4] = px + cc * (hx) - sn * (hy);
          cp[5] = py + sn * (hx) + cc * (hy);
          cp[6] = px + cc * (-hx) - sn * (hy);
          cp[7] = py + sn * (-hx) + cc * (hy);
          a.meta[g] =
              make_float4(px, py, 0.5f * sqrtf(pw * pw + ph * ph), pw * ph);
        }
      }
    }
  }
  __threadfence();
  grid.sync();

  // ---------- P6: prefilter + exact clip ----------
  {
    float* js_x = (float*)smem;                 // 2048
    float* js_y = (float*)(smem + 2048);        // 2048
    float* js_r = (float*)(smem + 4096);        // 2048
    float* js_a = (float*)(smem + 6144);        // 2048
    u32* list = (u32*)(smem + 8192);            // 8192
    volatile u32* lcnt = (volatile u32*)(smem + 16384);
    int b = bid >> 7;
    int i0 = (bid & 127) * 4;
    if (tid == 0) *lcnt = 0;
    for (int t = tid; t < K_SEL; t += 256) {
      float4 mj = a.meta[b * K_SEL + t];
      js_x[t] = mj.x; js_y[t] = mj.y; js_r[t] = mj.z; js_a[t] = mj.w;
    }
    __syncthreads();
    int i = i0 + (tid >> 6);
    int lane = tid & 63;
    float4 mi = a.meta[b * K_SEL + i];
    float cxi = mi.x, cyi = mi.y, ri = mi.z, ai = mi.w;
#pragma unroll
    for (int k = 0; k < 8; k++) {
      int j = lane + 64 * k;
      if (j <= i) continue;
      float ddx = cxi - js_x[j], ddy = cyi - js_y[j];
      float rr = ri + js_r[j];
      float d2 = ddx * ddx + ddy * ddy;
      if (d2 > rr * rr * 1.0001f) continue;
      float aj = js_a[j];
      float mnA = fminf(ai, aj), mxA = fmaxf(ai, aj);
      if (2.0f * mnA < 0.999f * mxA) continue;
      u32 p = atomicAdd((u32*)lcnt, 1u);
      list[p] = ((u32)i << 9) | (u32)j;
    }
    __syncthreads();
    u32 M = *lcnt;
    for (u32 l = tid; l < M; l += 256) {
      u32 pk = list[l];
      int i2 = (int)(pk >> 9);
      int j2 = (int)(pk & 511u);
      int gi2 = b * K_SEL + i2, gj2 = b * K_SEL + j2;
      const float* ci = a.corners + (size_t)gi2 * 8;
      const float* cj = a.corners + (size_t)gj2 * 8;
      float X[8], Y[8], bx[4], by[4];
#pragma unroll
      for (int m = 0; m < 4; m++) {
        X[m] = ci[2 * m]; Y[m] = ci[2 * m + 1];
        X[m + 4] = 0.f; Y[m + 4] = 0.f;
        bx[m] = cj[2 * m]; by[m] = cj[2 * m + 1];
      }
      int cnt2 = 4;
#pragma unroll
      for (int e = 0; e < 4; e++) {
        float axp = bx[e], ayp = by[e];
        float ex = bx[(e + 1) & 3] - axp, ey = by[(e + 1) & 3] - ayp;
        float d[8];
#pragma unroll
        for (int m = 0; m < 8; m++)
          d[m] = ex * (Y[m] - ayp) - ey * (X[m] - axp);
        float NX[8], NY[8];
#pragma unroll
        for (int s = 0; s < 8; s++) { NX[s] = 0.f; NY[s] = 0.f; }
        int oc = 0;
#pragma unroll
        for (int m = 0; m < 8; m++) {
          bool act = (m < cnt2);
          bool isLast = (m + 1 == cnt2);
          float dn = isLast ? d[0] : d[(m + 1) & 7];
          float xn = isLast ? X[0] : X[(m + 1) & 7];
          float yn = isLast ? Y[0] : Y[(m + 1) & 7];
          bool cin = (d[m] >= 0.f), nin = (dn >= 0.f);
          bool e1 = act && cin;
          bool e2 = act && (cin != nin);
#pragma unroll
          for (int s = 0; s < 8; s++) {
            bool w = e1 && (oc == s);
            NX[s] = w ? X[m] : NX[s];
            NY[s] = w ? Y[m] : NY[s];
          }
          oc += e1 ? 1 : 0;
          float den = d[m] - dn;
          float dd = (fabsf(den) < 1e-9f) ? 1e-9f : den;
          float tt = d[m] / dd;
          float ix = X[m] + tt * (xn - X[m]);
          float iy = Y[m] + tt * (yn - Y[m]);
#pragma unroll
          for (int s = 0; s < 8; s++) {
            bool w = e2 && (oc == s);
            NX[s] = w ? ix : NX[s];
            NY[s] = w ? iy : NY[s];
          }
          oc += e2 ? 1 : 0;
        }
        cnt2 = oc;
#pragma unroll
        for (int m = 0; m < 8; m++) { X[m] = NX[m]; Y[m] = NY[m]; }
      }
      float sum = 0.f;
#pragma unroll
      for (int m = 0; m < 8; m++) {
        bool act = (m < cnt2);
        bool isLast = (m + 1 == cnt2);
        float xn = isLast ? X[0] : X[(m + 1) & 7];
        float yn = isLast ? Y[0] : Y[(m + 1) & 7];
        float cr = X[m] * yn - Y[m] * xn;
        sum += act ? cr : 0.f;
      }
      float inter = (cnt2 >= 3) ? 0.5f * fabsf(sum) : 0.f;
      float ai2 = js_a[i2], aj2 = js_a[j2];
      float uni = ai2 + aj2 - inter;
      float iou = inter / fmaxf(uni, 1e-6f);
      if (iou > NMS_THR)
        atomicOr(&a.sup[((size_t)b * K_SEL + i2) * 8 + (j2 >> 6)],
                 1ull << (j2 & 63));
    }
  }
  __threadfence();
  grid.sync();

  // ---------- P7: sequential NMS sweep ----------
  if (bid < B) {
    int b = bid;
    u64* lsn = (u64*)smem;                 // 32768 B
    u64* vsh = (u64*)(smem + 32768);       // 64 B
    const u64* sb = a.sup + (size_t)b * K_SEL * 8;
    {
      const ulonglong2* s2 = (const ulonglong2*)sb;
      ulonglong2* l2 = (ulonglong2*)lsn;
      for (int k = tid; k < K_SEL * 4; k += 256) l2[k] = s2[k];
    }
    if (tid < 8) vsh[tid] = a.validw[b * 8 + tid];
    __syncthreads();
    if (tid < 64) {
      int lane = tid;
      u64 rem[8] = {0, 0, 0, 0, 0, 0, 0, 0};
      float* ko = a.out + a.off_keep + b * K_SEL;
      NCHUNK(0)
      NCHUNK(1)
      NCHUNK(2)
      NCHUNK(3)
      NCHUNK(4)
      NCHUNK(5)
      NCHUNK(6)
      NCHUNK(7)
    }
  }
}

extern "C" void kernel_launch(void* const* d_in, const int* in_sizes, int n_in,
                              void* d_out, int out_size, void* d_ws,
                              size_t ws_size, hipStream_t stream) {
  const float* logits = (const float*)d_in[0];
  const float* deltas = (const float*)d_in[1];
  const float* anchors = (const float*)d_in[2];
  float* out = (float*)d_out;
  int N = in_sizes[2] / 5;
  int B = in_sizes[1] / (N * 5);
  int C = (int)((long long)in_sizes[0] / ((long long)B * N));
  int BK = B * K_SEL;

  char* ws = (char*)d_ws;
  // zeroed region (contiguous): cnt(128B/img), validw, sup
  size_t o_cnt = 0;                               // 512 B
  size_t o_vw = o_cnt + 512;                      // 256 B
  size_t o_sup = o_vw + 256;                      // 128 KB
  size_t zero_end = o_sup + (size_t)B * K_SEL * 8 * 8;
  size_t o_cut = (zero_end + 255) & ~(size_t)255;
  size_t o_skey = (o_cut + 256 + 255) & ~(size_t)255;
  size_t o_cand = (o_skey + (size_t)B * N * 4 + 255) & ~(size_t)255;
  size_t o_corn = (o_cand + (size_t)B * CAP * 8 + 255) & ~(size_t)255;
  size_t o_meta = (o_corn + (size_t)BK * 8 * 4 + 255) & ~(size_t)255;
  size_t o_hp = (o_meta + (size_t)BK * 16 + 255) & ~(size_t)255;
  size_t o_hred = (o_hp + (size_t)B * SLABS * NBINS * 4 + 255) & ~(size_t)255;

  MegaArgs a;
  a.logits = logits;
  a.deltas = deltas;
  a.anchors = anchors;
  a.out = out;
  a.cnt = (u32*)(ws + o_cnt);
  a.validw = (u64*)(ws + o_vw);
  a.sup = (u64*)(ws + o_sup);
  a.cutT = (u32*)(ws + o_cut);
  a.skey = (u32*)(ws + o_skey);
  a.cand = (u64*)(ws + o_cand);
  a.corners = (float*)(ws + o_corn);
  a.meta = (float4*)(ws + o_meta);
  a.histp = (u32*)(ws + o_hp);
  a.hred = (u32*)(ws + o_hred);
  a.zbuf = (float4*)ws;
  a.nz4 = (int)(zero_end >> 4);
  a.N = N;
  a.C = C;
  a.off_scores = BK * 5;
  a.off_labels = BK * 6;
  a.off_keep = BK * 7;

  void* kargs[] = {&a};
  hipLaunchCooperativeKernel((const void*)k_mega, dim3(B * SLABS), dim3(256),
                             kargs, 0, stream);
}

// Round 15
// 153.365 us; speedup vs baseline: 4.3962x; 4.3962x over previous
//
#include <hip/hip_runtime.h>
#include <hip/hip_bf16.h>
#include <stdint.h>

typedef unsigned int u32;
typedef unsigned long long u64;

#define K_SEL 512
#define NBINS 4096
#define CAP 8192
#define SCORE_THR 0.05f
#define NMS_THR 0.5f
#define RPB 3072
#define SLABS 128

__device__ __forceinline__ u32 fkey(float x) {
  u32 u = __float_as_uint(x);
  return u ^ ((u32)((int)u >> 31) | 0x80000000u);
}
__device__ __forceinline__ float fkey_inv(u32 k) {
  u32 u = (k & 0x80000000u) ? (k ^ 0x80000000u) : ~k;
  return __uint_as_float(u);
}

// K1: fused per-anchor max + histogram (R13, unchanged). Coalesced float4
// LDS staging, bank-free stride-15 reads, non-atomic private slab flush.
__global__ __launch_bounds__(256) void k_maxhist(
    const float* __restrict__ logits, u32* __restrict__ skey,
    u32* __restrict__ histp, float4* __restrict__ zbuf, int nz4, int N) {
  int blk = blockIdx.x;
  int b = blk >> 7;
  int lb = blk & (SLABS - 1);
  for (int i = blk * 256 + threadIdx.x; i < nz4; i += gridDim.x * 256)
    zbuf[i] = make_float4(0.f, 0.f, 0.f, 0.f);
  __shared__ __align__(16) float tile[256 * 15];
  __shared__ u32 sh[NBINS];
  for (int i = threadIdx.x; i < NBINS; i += 256) sh[i] = 0;
  int r0 = lb * RPB;
  for (int c = 0; c < RPB / 256; c++) {
    int n0 = r0 + c * 256;
    if (n0 >= N) break;
    int nrow = min(256, N - n0);
    const float* src = logits + ((size_t)b * N + n0) * 15;
    int tot = nrow * 15;
    if (((tot & 3) == 0) && ((((size_t)src) & 15) == 0)) {
      const float4* s4 = (const float4*)src;
      float4* t4 = (float4*)tile;
      int n4 = tot >> 2;
      for (int i = threadIdx.x; i < n4; i += 256) t4[i] = s4[i];
    } else {
      for (int i = threadIdx.x; i < tot; i += 256) tile[i] = src[i];
    }
    __syncthreads();
    if (threadIdx.x < nrow) {
      const float* row = tile + threadIdx.x * 15;
      float mv = row[0];
      for (int cc = 1; cc < 15; cc++) mv = fmaxf(mv, row[cc]);
      u32 key = fkey(mv);
      skey[(size_t)b * N + n0 + threadIdx.x] = key;
      atomicAdd(&sh[key >> 20], 1u);
    }
    __syncthreads();
  }
  u32* hp = histp + (size_t)blk * NBINS;
  for (int i = threadIdx.x; i < NBINS; i += 256) hp[i] = sh[i];
}

// K2: wide slab reduction; LAST block per image (done-counter) computes the
// cutoff from the reduced hist via device-coherent atomic reads.
__global__ __launch_bounds__(256) void k_slabredcut(
    const u32* __restrict__ histp, u32* __restrict__ hred,
    u32* __restrict__ done3, u32* __restrict__ cutT) {
  int b = blockIdx.x >> 4;           // 16 blocks per image
  int part = blockIdx.x & 15;
  int bin = part * 256 + threadIdx.x;
  const u32* base = histp + (size_t)b * SLABS * NBINS + bin;
  u32 s = 0;
#pragma unroll 8
  for (int sl = 0; sl < SLABS; sl++) s += base[(size_t)sl * NBINS];
  hred[b * NBINS + bin] = s;
  __threadfence();
  __shared__ u32 lastflag;
  if (threadIdx.x == 0) lastflag = atomicAdd(&done3[b * 32], 1u);
  __syncthreads();
  if (lastflag != 15) return;
  // tail: cutoff for image b
  int t = threadIdx.x;
  u32* hb = hred + b * NBINS;
  u32 h[16];
  u32 sum = 0;
#pragma unroll
  for (int i = 0; i < 16; i++) {
    h[i] = atomicOr(&hb[t * 16 + i], 0u);
    sum += h[i];
  }
  __shared__ u32 cs[256];
  cs[t] = sum;
  __syncthreads();
  for (int off = 1; off < 256; off <<= 1) {
    u32 add = (t + off < 256) ? cs[t + off] : 0;
    __syncthreads();
    cs[t] += add;
    __syncthreads();
  }
  u32 run = (t < 255) ? cs[t + 1] : 0;
  for (int i = 15; i >= 0; i--) {
    u32 sfx = run + h[i];
    if (run < (u32)K_SEL && sfx >= (u32)K_SEL) cutT[b] = (u32)(t * 16 + i);
    run = sfx;
  }
}

// K3: compact candidates with bin >= cutT (R13, unchanged).
__global__ __launch_bounds__(256) void k_compact(
    const u32* __restrict__ skey, const u32* __restrict__ cutT,
    u64* __restrict__ cand, u32* __restrict__ cnt, int N) {
  int b = blockIdx.y;
  int n = blockIdx.x * 256 + threadIdx.x;
  __shared__ u32 lcnt, lbase;
  if (threadIdx.x == 0) lcnt = 0;
  __syncthreads();
  u32 key = 0;
  bool ok = false;
  u32 lpos = 0;
  if (n < N) {
    key = skey[(size_t)b * N + n];
    ok = (key >> 20) >= cutT[b];
  }
  if (ok) lpos = atomicAdd(&lcnt, 1u);
  __syncthreads();
  if (threadIdx.x == 0 && lcnt) lbase = atomicAdd(&cnt[b * 32], lcnt);
  __syncthreads();
  if (ok) {
    u32 pos = lbase + lpos;
    if (pos < CAP)
      cand[(size_t)b * CAP + pos] = ((u64)key << 32) | (u32)(~(u32)n);
  }
}

// K4: rank by counting, decode, emit packed meta float4 (R13, unchanged).
__global__ __launch_bounds__(256) void k_rankdecode(
    const u64* __restrict__ cand, const u32* __restrict__ cnt,
    const float* __restrict__ logits, const float* __restrict__ deltas,
    const float* __restrict__ anchors, float* __restrict__ out,
    float* __restrict__ corners, float4* __restrict__ meta,
    u64* __restrict__ validw, int N, int C, int off_scores, int off_labels) {
  int b = blockIdx.y;
  int M = (int)min(cnt[b * 32], (u32)CAP);
  if (blockIdx.x * 256 >= (u32)M) return;
  int m = blockIdx.x * 256 + threadIdx.x;
  u64 my = (m < M) ? cand[(size_t)b * CAP + m] : 0ull;
  int rank = 0;
  __shared__ u64 t[256];
  for (int j0 = 0; j0 < M; j0 += 256) {
    int j = j0 + threadIdx.x;
    t[threadIdx.x] = (j < M) ? cand[(size_t)b * CAP + j] : 0ull;
    __syncthreads();
    int lim = min(256, M - j0);
    for (int jj = 0; jj < lim; jj++) rank += (t[jj] > my) ? 1 : 0;
    __syncthreads();
  }
  if (m >= M || rank >= K_SEL) return;
  int g = b * K_SEL + rank;
  u32 key = (u32)(my >> 32);
  int idx = (int)(~(u32)my);
  float ml = fkey_inv(key);
  float score = 1.0f / (1.0f + expf(-ml));
  const float* lr = logits + ((size_t)b * N + idx) * C;
  float bv = lr[0];
  int lab = 0;
  for (int c = 1; c < C; c++) {
    float v = lr[c];
    if (v > bv) { bv = v; lab = c; }
  }
  const float* ar = anchors + (size_t)idx * 5;
  const float* dr = deltas + ((size_t)b * N + idx) * 5;
  float ax = ar[0], ay = ar[1], aw = ar[2], ah = ar[3], aa = ar[4];
  float dx = dr[0], dy = dr[1], dwv = dr[2], dhv = dr[3], da = dr[4];
  float px = ax + dx * aw;
  float py = ay + dy * ah;
  float pw = aw * expf(fminf(fmaxf(dwv, -4.0f), 4.0f));
  float ph = ah * expf(fminf(fmaxf(dhv, -4.0f), 4.0f));
  float pa = aa + da * 57.295779513082323f;
  float* ob = out + (size_t)g * 5;
  ob[0] = px; ob[1] = py; ob[2] = pw; ob[3] = ph; ob[4] = pa;
  out[off_scores + g] = score;
  out[off_labels + g] = (float)lab;
  if (score > SCORE_THR) atomicOr(&validw[g >> 6], 1ull << (g & 63));
  float tt = pa * 0.017453292519943295f;
  float cc = cosf(tt), sn = sinf(tt);
  float hx = pw * 0.5f, hy = ph * 0.5f;
  float* cp = corners + (size_t)g * 8;
  cp[0] = px + cc * (-hx) - sn * (-hy);
  cp[1] = py + sn * (-hx) + cc * (-hy);
  cp[2] = px + cc * (hx) - sn * (-hy);
  cp[3] = py + sn * (hx) + cc * (-hy);
  cp[4] = px + cc * (hx) - sn * (hy);
  cp[5] = py + sn * (hx) + cc * (hy);
  cp[6] = px + cc * (-hx) - sn * (hy);
  cp[7] = py + sn * (-hx) + cc * (hy);
  meta[g] = make_float4(px, py, 0.5f * sqrtf(pw * pw + ph * ph), pw * ph);
}

// NMS sweep macros (single-word chain + catch-up ORs), R13 unchanged.
#define NSTEP(PB, S, cc)                                                   \
  {                                                                        \
    u64 live_ = ((vv >> (S)) & ~(rw >> (S))) & 1ull;                       \
    u64 m_ = (u64)0 - live_;                                               \
    rw |= PB & m_;                                                         \
    km |= live_ << (S);                                                    \
    if ((S) < 48) PB = lsn[((cc)*64 + (S) + 16) * 8 + (cc)];               \
  }

#define NGROUP16(S0, cc)                                                   \
  NSTEP(P0, (S0) + 0, cc) NSTEP(P1, (S0) + 1, cc)                          \
  NSTEP(P2, (S0) + 2, cc) NSTEP(P3, (S0) + 3, cc)                          \
  NSTEP(P4, (S0) + 4, cc) NSTEP(P5, (S0) + 5, cc)                          \
  NSTEP(P6, (S0) + 6, cc) NSTEP(P7, (S0) + 7, cc)                          \
  NSTEP(P8, (S0) + 8, cc) NSTEP(P9, (S0) + 9, cc)                          \
  NSTEP(P10, (S0) + 10, cc) NSTEP(P11, (S0) + 11, cc)                      \
  NSTEP(P12, (S0) + 12, cc) NSTEP(P13, (S0) + 13, cc)                      \
  NSTEP(P14, (S0) + 14, cc) NSTEP(P15, (S0) + 15, cc)

#define NCHUNK(cc)                                                         \
  {                                                                        \
    u64 vv = vsh[cc];                                                      \
    u64 rw = rem[cc];                                                      \
    u64 km = 0;                                                            \
    u64 P0 = lsn[((cc)*64 + 0) * 8 + (cc)];                                \
    u64 P1 = lsn[((cc)*64 + 1) * 8 + (cc)];                                \
    u64 P2 = lsn[((cc)*64 + 2) * 8 + (cc)];                                \
    u64 P3 = lsn[((cc)*64 + 3) * 8 + (cc)];                                \
    u64 P4 = lsn[((cc)*64 + 4) * 8 + (cc)];                                \
    u64 P5 = lsn[((cc)*64 + 5) * 8 + (cc)];                                \
    u64 P6 = lsn[((cc)*64 + 6) * 8 + (cc)];                                \
    u64 P7 = lsn[((cc)*64 + 7) * 8 + (cc)];                                \
    u64 P8 = lsn[((cc)*64 + 8) * 8 + (cc)];                                \
    u64 P9 = lsn[((cc)*64 + 9) * 8 + (cc)];                                \
    u64 P10 = lsn[((cc)*64 + 10) * 8 + (cc)];                              \
    u64 P11 = lsn[((cc)*64 + 11) * 8 + (cc)];                              \
    u64 P12 = lsn[((cc)*64 + 12) * 8 + (cc)];                              \
    u64 P13 = lsn[((cc)*64 + 13) * 8 + (cc)];                              \
    u64 P14 = lsn[((cc)*64 + 14) * 8 + (cc)];                              \
    u64 P15 = lsn[((cc)*64 + 15) * 8 + (cc)];                              \
    NGROUP16(0, cc) NGROUP16(16, cc) NGROUP16(32, cc) NGROUP16(48, cc)     \
    u64 kk = km;                                                           \
    while (kk) {                                                           \
      int r_ = (cc)*64 + __builtin_ctzll(kk);                              \
      kk &= kk - 1ull;                                                     \
      const u64* rb_ = lsn + r_ * 8;                                       \
      rem[0] |= rb_[0]; rem[1] |= rb_[1]; rem[2] |= rb_[2];                \
      rem[3] |= rb_[3]; rem[4] |= rb_[4]; rem[5] |= rb_[5];                \
      rem[6] |= rb_[6]; rem[7] |= rb_[7];                                  \
    }                                                                      \
    ko[(cc)*64 + lane] = (float)((km >> lane) & 1ull);                     \
  }

// K5: fused prefilter + exact clip; LAST block per image (done-counter)
// runs the NMS sweep (sup staged via device-coherent atomic reads).
__global__ __launch_bounds__(256) void k_pairclipnms(
    const float4* __restrict__ meta, const float* __restrict__ corners,
    u64* __restrict__ sup, const u64* __restrict__ validw,
    u32* __restrict__ done2, float* __restrict__ keep_out) {
  __shared__ __align__(16) char smem[33024];
  float* js_x = (float*)smem;                 // 2048
  float* js_y = (float*)(smem + 2048);        // 2048
  float* js_r = (float*)(smem + 4096);        // 2048
  float* js_a = (float*)(smem + 6144);        // 2048
  u32* list = (u32*)(smem + 8192);            // 8192
  u32* lcnt = (u32*)(smem + 16384);
  int b = blockIdx.x >> 7;          // 128 blocks per image
  int i0 = (blockIdx.x & 127) * 4;  // 4 i-rows per block (one per wave)
  if (threadIdx.x == 0) *lcnt = 0;
  for (int t = threadIdx.x; t < K_SEL; t += 256) {
    float4 mj = meta[b * K_SEL + t];
    js_x[t] = mj.x; js_y[t] = mj.y; js_r[t] = mj.z; js_a[t] = mj.w;
  }
  __syncthreads();
  int i = i0 + (threadIdx.x >> 6);
  int lane = threadIdx.x & 63;
  float4 mi = meta[b * K_SEL + i];
  float cxi = mi.x, cyi = mi.y, ri = mi.z, ai = mi.w;
#pragma unroll
  for (int k = 0; k < 8; k++) {
    int j = lane + 64 * k;
    if (j <= i) continue;
    float ddx = cxi - js_x[j], ddy = cyi - js_y[j];
    float rr = ri + js_r[j];
    float d2 = ddx * ddx + ddy * ddy;
    if (d2 > rr * rr * 1.0001f) continue;
    float aj = js_a[j];
    float mnA = fminf(ai, aj), mxA = fmaxf(ai, aj);
    if (2.0f * mnA < 0.999f * mxA) continue;
    u32 p = atomicAdd(lcnt, 1u);
    list[p] = ((u32)i << 9) | (u32)j;
  }
  __syncthreads();
  u32 M = *lcnt;
  for (u32 l = threadIdx.x; l < M; l += 256) {
    u32 pk = list[l];
    int i2 = (int)(pk >> 9);
    int j2 = (int)(pk & 511u);
    int gi2 = b * K_SEL + i2, gj2 = b * K_SEL + j2;
    const float* ci = corners + (size_t)gi2 * 8;
    const float* cj = corners + (size_t)gj2 * 8;
    float X[8], Y[8], bx[4], by[4];
#pragma unroll
    for (int m = 0; m < 4; m++) {
      X[m] = ci[2 * m]; Y[m] = ci[2 * m + 1];
      X[m + 4] = 0.f; Y[m + 4] = 0.f;
      bx[m] = cj[2 * m]; by[m] = cj[2 * m + 1];
    }
    int cnt2 = 4;
#pragma unroll
    for (int e = 0; e < 4; e++) {
      float axp = bx[e], ayp = by[e];
      float ex = bx[(e + 1) & 3] - axp, ey = by[(e + 1) & 3] - ayp;
      float d[8];
#pragma unroll
      for (int m = 0; m < 8; m++)
        d[m] = ex * (Y[m] - ayp) - ey * (X[m] - axp);
      float NX[8], NY[8];
#pragma unroll
      for (int s = 0; s < 8; s++) { NX[s] = 0.f; NY[s] = 0.f; }
      int oc = 0;
#pragma unroll
      for (int m = 0; m < 8; m++) {
        bool act = (m < cnt2);
        bool isLast = (m + 1 == cnt2);
        float dn = isLast ? d[0] : d[(m + 1) & 7];
        float xn = isLast ? X[0] : X[(m + 1) & 7];
        float yn = isLast ? Y[0] : Y[(m + 1) & 7];
        bool cin = (d[m] >= 0.f), nin = (dn >= 0.f);
        bool e1 = act && cin;
        bool e2 = act && (cin != nin);
#pragma unroll
        for (int s = 0; s < 8; s++) {
          bool w = e1 && (oc == s);
          NX[s] = w ? X[m] : NX[s];
          NY[s] = w ? Y[m] : NY[s];
        }
        oc += e1 ? 1 : 0;
        float den = d[m] - dn;
        float dd = (fabsf(den) < 1e-9f) ? 1e-9f : den;
        float tt = d[m] / dd;
        float ix = X[m] + tt * (xn - X[m]);
        float iy = Y[m] + tt * (yn - Y[m]);
#pragma unroll
        for (int s = 0; s < 8; s++) {
          bool w = e2 && (oc == s);
          NX[s] = w ? ix : NX[s];
          NY[s] = w ? iy : NY[s];
        }
        oc += e2 ? 1 : 0;
      }
      cnt2 = oc;
#pragma unroll
      for (int m = 0; m < 8; m++) { X[m] = NX[m]; Y[m] = NY[m]; }
    }
    float sum = 0.f;
#pragma unroll
    for (int m = 0; m < 8; m++) {
      bool act = (m < cnt2);
      bool isLast = (m + 1 == cnt2);
      float xn = isLast ? X[0] : X[(m + 1) & 7];
      float yn = isLast ? Y[0] : Y[(m + 1) & 7];
      float cr = X[m] * yn - Y[m] * xn;
      sum += act ? cr : 0.f;
    }
    float inter = (cnt2 >= 3) ? 0.5f * fabsf(sum) : 0.f;
    float ai2 = js_a[i2], aj2 = js_a[j2];
    float uni = ai2 + aj2 - inter;
    float iou = inter / fmaxf(uni, 1e-6f);
    if (iou > NMS_THR)
      atomicOr(&sup[((size_t)b * K_SEL + i2) * 8 + (j2 >> 6)],
               1ull << (j2 & 63));
  }
  // ---- last block per image: NMS sweep ----
  __syncthreads();
  __threadfence();
  __shared__ u32 lastflag;
  if (threadIdx.x == 0) lastflag = atomicAdd(&done2[b * 32], 1u);
  __syncthreads();
  if (lastflag != 127) return;
  u64* lsn = (u64*)smem;            // 32768 B (reuses prefilter smem)
  __shared__ u64 vsh[8];
  u64* sb = sup + (size_t)b * K_SEL * 8;
  for (int k2 = threadIdx.x; k2 < K_SEL * 8; k2 += 256)
    lsn[k2] = atomicOr(&sb[k2], 0ull);
  if (threadIdx.x < 8) vsh[threadIdx.x] = validw[b * 8 + threadIdx.x];
  __syncthreads();
  if (threadIdx.x >= 64) return;
  int lane2 = threadIdx.x;
  {
    int lane = lane2;
    u64 rem[8] = {0, 0, 0, 0, 0, 0, 0, 0};
    float* ko = keep_out + b * K_SEL;
    NCHUNK(0)
    NCHUNK(1)
    NCHUNK(2)
    NCHUNK(3)
    NCHUNK(4)
    NCHUNK(5)
    NCHUNK(6)
    NCHUNK(7)
  }
}

extern "C" void kernel_launch(void* const* d_in, const int* in_sizes, int n_in,
                              void* d_out, int out_size, void* d_ws,
                              size_t ws_size, hipStream_t stream) {
  const float* logits = (const float*)d_in[0];
  const float* deltas = (const float*)d_in[1];
  const float* anchors = (const float*)d_in[2];
  float* out = (float*)d_out;
  int N = in_sizes[2] / 5;
  int B = in_sizes[1] / (N * 5);
  int C = (int)((long long)in_sizes[0] / ((long long)B * N));
  int BK = B * K_SEL;

  char* ws = (char*)d_ws;
  // zeroed region (contiguous): cnt, done2, done3 (128B/img each), validw, sup
  size_t o_cnt = 0;                               // 512 B
  size_t o_done2 = o_cnt + 512;                   // 512 B
  size_t o_done3 = o_done2 + 512;                 // 512 B
  size_t o_vw = o_done3 + 512;                    // 256 B
  size_t o_sup = o_vw + 256;                      // 128 KB
  size_t zero_end = o_sup + (size_t)B * K_SEL * 8 * 8;
  size_t o_cut = (zero_end + 255) & ~(size_t)255;
  size_t o_skey = (o_cut + 256 + 255) & ~(size_t)255;
  size_t o_cand = (o_skey + (size_t)B * N * 4 + 255) & ~(size_t)255;
  size_t o_corn = (o_cand + (size_t)B * CAP * 8 + 255) & ~(size_t)255;
  size_t o_meta = (o_corn + (size_t)BK * 8 * 4 + 255) & ~(size_t)255;
  size_t o_hp = (o_meta + (size_t)BK * 16 + 255) & ~(size_t)255;
  size_t o_hred = (o_hp + (size_t)B * SLABS * NBINS * 4 + 255) & ~(size_t)255;

  u32* cnt = (u32*)(ws + o_cnt);
  u32* done2 = (u32*)(ws + o_done2);
  u32* done3 = (u32*)(ws + o_done3);
  u64* validw = (u64*)(ws + o_vw);
  u64* sup = (u64*)(ws + o_sup);
  u32* cutT = (u32*)(ws + o_cut);
  u32* skey = (u32*)(ws + o_skey);
  u64* cand = (u64*)(ws + o_cand);
  float* corners = (float*)(ws + o_corn);
  float4* meta = (float4*)(ws + o_meta);
  u32* histp = (u32*)(ws + o_hp);
  u32* hred = (u32*)(ws + o_hred);

  int nz4 = (int)(zero_end >> 4);

  int nb = (N + 255) / 256;
  k_maxhist<<<B * SLABS, 256, 0, stream>>>(logits, skey, histp, (float4*)ws,
                                           nz4, N);
  k_slabredcut<<<B * (NBINS / 256), 256, 0, stream>>>(histp, hred, done3,
                                                      cutT);
  k_compact<<<dim3(nb, B), 256, 0, stream>>>(skey, cutT, cand, cnt, N);
  int off_scores = BK * 5, off_labels = BK * 6, off_keep = BK * 7;
  k_rankdecode<<<dim3(CAP / 256, B), 256, 0, stream>>>(
      cand, cnt, logits, deltas, anchors, out, corners, meta, validw, N, C,
      off_scores, off_labels);
  k_pairclipnms<<<B * 128, 256, 0, stream>>>(meta, corners, sup, validw,
                                             done2, out + off_keep);
}

// Round 16
// 125.299 us; speedup vs baseline: 5.3809x; 1.2240x over previous
//
#include <hip/hip_runtime.h>
#include <hip/hip_bf16.h>
#include <stdint.h>

typedef unsigned int u32;
typedef unsigned long long u64;

#define K_SEL 512
#define NBINS 4096
#define CAP 8192
#define SCORE_THR 0.05f
#define NMS_THR 0.5f
#define RPB 3072
#define SLABS 128

__device__ __forceinline__ u32 fkey(float x) {
  u32 u = __float_as_uint(x);
  return u ^ ((u32)((int)u >> 31) | 0x80000000u);
}
__device__ __forceinline__ float fkey_inv(u32 k) {
  u32 u = (k & 0x80000000u) ? (k ^ 0x80000000u) : ~k;
  return __uint_as_float(u);
}

// K1: fused per-anchor max + histogram (R13, unchanged).
__global__ __launch_bounds__(256) void k_maxhist(
    const float* __restrict__ logits, u32* __restrict__ skey,
    u32* __restrict__ histp, float4* __restrict__ zbuf, int nz4, int N) {
  int blk = blockIdx.x;
  int b = blk >> 7;
  int lb = blk & (SLABS - 1);
  for (int i = blk * 256 + threadIdx.x; i < nz4; i += gridDim.x * 256)
    zbuf[i] = make_float4(0.f, 0.f, 0.f, 0.f);
  __shared__ __align__(16) float tile[256 * 15];
  __shared__ u32 sh[NBINS];
  for (int i = threadIdx.x; i < NBINS; i += 256) sh[i] = 0;
  int r0 = lb * RPB;
  for (int c = 0; c < RPB / 256; c++) {
    int n0 = r0 + c * 256;
    if (n0 >= N) break;
    int nrow = min(256, N - n0);
    const float* src = logits + ((size_t)b * N + n0) * 15;
    int tot = nrow * 15;
    if (((tot & 3) == 0) && ((((size_t)src) & 15) == 0)) {
      const float4* s4 = (const float4*)src;
      float4* t4 = (float4*)tile;
      int n4 = tot >> 2;
      for (int i = threadIdx.x; i < n4; i += 256) t4[i] = s4[i];
    } else {
      for (int i = threadIdx.x; i < tot; i += 256) tile[i] = src[i];
    }
    __syncthreads();
    if (threadIdx.x < nrow) {
      const float* row = tile + threadIdx.x * 15;
      float mv = row[0];
      for (int cc = 1; cc < 15; cc++) mv = fmaxf(mv, row[cc]);
      u32 key = fkey(mv);
      skey[(size_t)b * N + n0 + threadIdx.x] = key;
      atomicAdd(&sh[key >> 20], 1u);
    }
    __syncthreads();
  }
  u32* hp = histp + (size_t)blk * NBINS;
  for (int i = threadIdx.x; i < NBINS; i += 256) hp[i] = sh[i];
}

// K2: wide slab reduction; LAST block per image (done-counter) computes the
// cutoff (16KB atomic-read tail — measured neutral in R15).
__global__ __launch_bounds__(256) void k_slabredcut(
    const u32* __restrict__ histp, u32* __restrict__ hred,
    u32* __restrict__ done3, u32* __restrict__ cutT) {
  int b = blockIdx.x >> 4;           // 16 blocks per image
  int part = blockIdx.x & 15;
  int bin = part * 256 + threadIdx.x;
  const u32* base = histp + (size_t)b * SLABS * NBINS + bin;
  u32 s = 0;
#pragma unroll 8
  for (int sl = 0; sl < SLABS; sl++) s += base[(size_t)sl * NBINS];
  hred[b * NBINS + bin] = s;
  __threadfence();
  __shared__ u32 lastflag;
  if (threadIdx.x == 0) lastflag = atomicAdd(&done3[b * 32], 1u);
  __syncthreads();
  if (lastflag != 15) return;
  int t = threadIdx.x;
  u32* hb = hred + b * NBINS;
  u32 h[16];
  u32 sum = 0;
#pragma unroll
  for (int i = 0; i < 16; i++) {
    h[i] = atomicOr(&hb[t * 16 + i], 0u);
    sum += h[i];
  }
  __shared__ u32 cs[256];
  cs[t] = sum;
  __syncthreads();
  for (int off = 1; off < 256; off <<= 1) {
    u32 add = (t + off < 256) ? cs[t + off] : 0;
    __syncthreads();
    cs[t] += add;
    __syncthreads();
  }
  u32 run = (t < 255) ? cs[t + 1] : 0;
  for (int i = 15; i >= 0; i--) {
    u32 sfx = run + h[i];
    if (run < (u32)K_SEL && sfx >= (u32)K_SEL) cutT[b] = (u32)(t * 16 + i);
    run = sfx;
  }
}

// K3: compact candidates with bin >= cutT (R13, unchanged).
__global__ __launch_bounds__(256) void k_compact(
    const u32* __restrict__ skey, const u32* __restrict__ cutT,
    u64* __restrict__ cand, u32* __restrict__ cnt, int N) {
  int b = blockIdx.y;
  int n = blockIdx.x * 256 + threadIdx.x;
  __shared__ u32 lcnt, lbase;
  if (threadIdx.x == 0) lcnt = 0;
  __syncthreads();
  u32 key = 0;
  bool ok = false;
  u32 lpos = 0;
  if (n < N) {
    key = skey[(size_t)b * N + n];
    ok = (key >> 20) >= cutT[b];
  }
  if (ok) lpos = atomicAdd(&lcnt, 1u);
  __syncthreads();
  if (threadIdx.x == 0 && lcnt) lbase = atomicAdd(&cnt[b * 32], lcnt);
  __syncthreads();
  if (ok) {
    u32 pos = lbase + lpos;
    if (pos < CAP)
      cand[(size_t)b * CAP + pos] = ((u64)key << 32) | (u32)(~(u32)n);
  }
}

// K4: rank by counting, decode, emit packed meta float4 (R13, unchanged).
__global__ __launch_bounds__(256) void k_rankdecode(
    const u64* __restrict__ cand, const u32* __restrict__ cnt,
    const float* __restrict__ logits, const float* __restrict__ deltas,
    const float* __restrict__ anchors, float* __restrict__ out,
    float* __restrict__ corners, float4* __restrict__ meta,
    u64* __restrict__ validw, int N, int C, int off_scores, int off_labels) {
  int b = blockIdx.y;
  int M = (int)min(cnt[b * 32], (u32)CAP);
  if (blockIdx.x * 256 >= (u32)M) return;
  int m = blockIdx.x * 256 + threadIdx.x;
  u64 my = (m < M) ? cand[(size_t)b * CAP + m] : 0ull;
  int rank = 0;
  __shared__ u64 t[256];
  for (int j0 = 0; j0 < M; j0 += 256) {
    int j = j0 + threadIdx.x;
    t[threadIdx.x] = (j < M) ? cand[(size_t)b * CAP + j] : 0ull;
    __syncthreads();
    int lim = min(256, M - j0);
    for (int jj = 0; jj < lim; jj++) rank += (t[jj] > my) ? 1 : 0;
    __syncthreads();
  }
  if (m >= M || rank >= K_SEL) return;
  int g = b * K_SEL + rank;
  u32 key = (u32)(my >> 32);
  int idx = (int)(~(u32)my);
  float ml = fkey_inv(key);
  float score = 1.0f / (1.0f + expf(-ml));
  const float* lr = logits + ((size_t)b * N + idx) * C;
  float bv = lr[0];
  int lab = 0;
  for (int c = 1; c < C; c++) {
    float v = lr[c];
    if (v > bv) { bv = v; lab = c; }
  }
  const float* ar = anchors + (size_t)idx * 5;
  const float* dr = deltas + ((size_t)b * N + idx) * 5;
  float ax = ar[0], ay = ar[1], aw = ar[2], ah = ar[3], aa = ar[4];
  float dx = dr[0], dy = dr[1], dwv = dr[2], dhv = dr[3], da = dr[4];
  float px = ax + dx * aw;
  float py = ay + dy * ah;
  float pw = aw * expf(fminf(fmaxf(dwv, -4.0f), 4.0f));
  float ph = ah * expf(fminf(fmaxf(dhv, -4.0f), 4.0f));
  float pa = aa + da * 57.295779513082323f;
  float* ob = out + (size_t)g * 5;
  ob[0] = px; ob[1] = py; ob[2] = pw; ob[3] = ph; ob[4] = pa;
  out[off_scores + g] = score;
  out[off_labels + g] = (float)lab;
  if (score > SCORE_THR) atomicOr(&validw[g >> 6], 1ull << (g & 63));
  float tt = pa * 0.017453292519943295f;
  float cc = cosf(tt), sn = sinf(tt);
  float hx = pw * 0.5f, hy = ph * 0.5f;
  float* cp = corners + (size_t)g * 8;
  cp[0] = px + cc * (-hx) - sn * (-hy);
  cp[1] = py + sn * (-hx) + cc * (-hy);
  cp[2] = px + cc * (hx) - sn * (-hy);
  cp[3] = py + sn * (hx) + cc * (-hy);
  cp[4] = px + cc * (hx) - sn * (hy);
  cp[5] = py + sn * (hx) + cc * (hy);
  cp[6] = px + cc * (-hx) - sn * (hy);
  cp[7] = py + sn * (-hx) + cc * (hy);
  meta[g] = make_float4(px, py, 0.5f * sqrtf(pw * pw + ph * ph), pw * ph);
}

// K5: fused prefilter + exact clip (R13, unchanged; 16.5 KB LDS).
__global__ __launch_bounds__(256) void k_pairclip(
    const float4* __restrict__ meta, const float* __restrict__ corners,
    u64* __restrict__ sup) {
  int b = blockIdx.x >> 7;
  int i0 = (blockIdx.x & 127) * 4;
  __shared__ float js_x[K_SEL], js_y[K_SEL], js_r[K_SEL], js_a[K_SEL];
  __shared__ u32 list[2048];
  __shared__ u32 lcnt;
  if (threadIdx.x == 0) lcnt = 0;
  for (int t = threadIdx.x; t < K_SEL; t += 256) {
    float4 mj = meta[b * K_SEL + t];
    js_x[t] = mj.x; js_y[t] = mj.y; js_r[t] = mj.z; js_a[t] = mj.w;
  }
  __syncthreads();
  int i = i0 + (threadIdx.x >> 6);
  int lane = threadIdx.x & 63;
  float4 mi = meta[b * K_SEL + i];
  float cxi = mi.x, cyi = mi.y, ri = mi.z, ai = mi.w;
#pragma unroll
  for (int k = 0; k < 8; k++) {
    int j = lane + 64 * k;
    if (j <= i) continue;
    float ddx = cxi - js_x[j], ddy = cyi - js_y[j];
    float rr = ri + js_r[j];
    float d2 = ddx * ddx + ddy * ddy;
    if (d2 > rr * rr * 1.0001f) continue;
    float aj = js_a[j];
    float mnA = fminf(ai, aj), mxA = fmaxf(ai, aj);
    if (2.0f * mnA < 0.999f * mxA) continue;
    u32 p = atomicAdd(&lcnt, 1u);
    list[p] = ((u32)i << 9) | (u32)j;
  }
  __syncthreads();
  u32 M = lcnt;
  for (u32 l = threadIdx.x; l < M; l += 256) {
    u32 pk = list[l];
    int i2 = (int)(pk >> 9);
    int j2 = (int)(pk & 511u);
    int gi2 = b * K_SEL + i2, gj2 = b * K_SEL + j2;
    const float* ci = corners + (size_t)gi2 * 8;
    const float* cj = corners + (size_t)gj2 * 8;
    float X[8], Y[8], bx[4], by[4];
#pragma unroll
    for (int m = 0; m < 4; m++) {
      X[m] = ci[2 * m]; Y[m] = ci[2 * m + 1];
      X[m + 4] = 0.f; Y[m + 4] = 0.f;
      bx[m] = cj[2 * m]; by[m] = cj[2 * m + 1];
    }
    int cnt2 = 4;
#pragma unroll
    for (int e = 0; e < 4; e++) {
      float axp = bx[e], ayp = by[e];
      float ex = bx[(e + 1) & 3] - axp, ey = by[(e + 1) & 3] - ayp;
      float d[8];
#pragma unroll
      for (int m = 0; m < 8; m++)
        d[m] = ex * (Y[m] - ayp) - ey * (X[m] - axp);
      float NX[8], NY[8];
#pragma unroll
      for (int s = 0; s < 8; s++) { NX[s] = 0.f; NY[s] = 0.f; }
      int oc = 0;
#pragma unroll
      for (int m = 0; m < 8; m++) {
        bool act = (m < cnt2);
        bool isLast = (m + 1 == cnt2);
        float dn = isLast ? d[0] : d[(m + 1) & 7];
        float xn = isLast ? X[0] : X[(m + 1) & 7];
        float yn = isLast ? Y[0] : Y[(m + 1) & 7];
        bool cin = (d[m] >= 0.f), nin = (dn >= 0.f);
        bool e1 = act && cin;
        bool e2 = act && (cin != nin);
#pragma unroll
        for (int s = 0; s < 8; s++) {
          bool w = e1 && (oc == s);
          NX[s] = w ? X[m] : NX[s];
          NY[s] = w ? Y[m] : NY[s];
        }
        oc += e1 ? 1 : 0;
        float den = d[m] - dn;
        float dd = (fabsf(den) < 1e-9f) ? 1e-9f : den;
        float tt = d[m] / dd;
        float ix = X[m] + tt * (xn - X[m]);
        float iy = Y[m] + tt * (yn - Y[m]);
#pragma unroll
        for (int s = 0; s < 8; s++) {
          bool w = e2 && (oc == s);
          NX[s] = w ? ix : NX[s];
          NY[s] = w ? iy : NY[s];
        }
        oc += e2 ? 1 : 0;
      }
      cnt2 = oc;
#pragma unroll
      for (int m = 0; m < 8; m++) { X[m] = NX[m]; Y[m] = NY[m]; }
    }
    float sum = 0.f;
#pragma unroll
    for (int m = 0; m < 8; m++) {
      bool act = (m < cnt2);
      bool isLast = (m + 1 == cnt2);
      float xn = isLast ? X[0] : X[(m + 1) & 7];
      float yn = isLast ? Y[0] : Y[(m + 1) & 7];
      float cr = X[m] * yn - Y[m] * xn;
      sum += act ? cr : 0.f;
    }
    float inter = (cnt2 >= 3) ? 0.5f * fabsf(sum) : 0.f;
    float ai2 = js_a[i2], aj2 = js_a[j2];
    float uni = ai2 + aj2 - inter;
    float iou = inter / fmaxf(uni, 1e-6f);
    if (iou > NMS_THR)
      atomicOr(&sup[((size_t)b * K_SEL + i2) * 8 + (j2 >> 6)],
               1ull << (j2 & 63));
  }
}

// K6: sequential NMS sweep (R13, unchanged).
#define NSTEP(PB, S, cc)                                                   \
  {                                                                        \
    u64 live_ = ((vv >> (S)) & ~(rw >> (S))) & 1ull;                       \
    u64 m_ = (u64)0 - live_;                                               \
    rw |= PB & m_;                                                         \
    km |= live_ << (S);                                                    \
    if ((S) < 48) PB = lsn[((cc)*64 + (S) + 16) * 8 + (cc)];               \
  }

#define NGROUP16(S0, cc)                                                   \
  NSTEP(P0, (S0) + 0, cc) NSTEP(P1, (S0) + 1, cc)                          \
  NSTEP(P2, (S0) + 2, cc) NSTEP(P3, (S0) + 3, cc)                          \
  NSTEP(P4, (S0) + 4, cc) NSTEP(P5, (S0) + 5, cc)                          \
  NSTEP(P6, (S0) + 6, cc) NSTEP(P7, (S0) + 7, cc)                          \
  NSTEP(P8, (S0) + 8, cc) NSTEP(P9, (S0) + 9, cc)                          \
  NSTEP(P10, (S0) + 10, cc) NSTEP(P11, (S0) + 11, cc)                      \
  NSTEP(P12, (S0) + 12, cc) NSTEP(P13, (S0) + 13, cc)                      \
  NSTEP(P14, (S0) + 14, cc) NSTEP(P15, (S0) + 15, cc)

#define NCHUNK(cc)                                                         \
  {                                                                        \
    u64 vv = vsh[cc];                                                      \
    u64 rw = rem[cc];                                                      \
    u64 km = 0;                                                            \
    u64 P0 = lsn[((cc)*64 + 0) * 8 + (cc)];                                \
    u64 P1 = lsn[((cc)*64 + 1) * 8 + (cc)];                                \
    u64 P2 = lsn[((cc)*64 + 2) * 8 + (cc)];                                \
    u64 P3 = lsn[((cc)*64 + 3) * 8 + (cc)];                                \
    u64 P4 = lsn[((cc)*64 + 4) * 8 + (cc)];                                \
    u64 P5 = lsn[((cc)*64 + 5) * 8 + (cc)];                                \
    u64 P6 = lsn[((cc)*64 + 6) * 8 + (cc)];                                \
    u64 P7 = lsn[((cc)*64 + 7) * 8 + (cc)];                                \
    u64 P8 = lsn[((cc)*64 + 8) * 8 + (cc)];                                \
    u64 P9 = lsn[((cc)*64 + 9) * 8 + (cc)];                                \
    u64 P10 = lsn[((cc)*64 + 10) * 8 + (cc)];                              \
    u64 P11 = lsn[((cc)*64 + 11) * 8 + (cc)];                              \
    u64 P12 = lsn[((cc)*64 + 12) * 8 + (cc)];                              \
    u64 P13 = lsn[((cc)*64 + 13) * 8 + (cc)];                              \
    u64 P14 = lsn[((cc)*64 + 14) * 8 + (cc)];                              \
    u64 P15 = lsn[((cc)*64 + 15) * 8 + (cc)];                              \
    NGROUP16(0, cc) NGROUP16(16, cc) NGROUP16(32, cc) NGROUP16(48, cc)     \
    u64 kk = km;                                                           \
    while (kk) {                                                           \
      int r_ = (cc)*64 + __builtin_ctzll(kk);                              \
      kk &= kk - 1ull;                                                     \
      const u64* rb_ = lsn + r_ * 8;                                       \
      rem[0] |= rb_[0]; rem[1] |= rb_[1]; rem[2] |= rb_[2];                \
      rem[3] |= rb_[3]; rem[4] |= rb_[4]; rem[5] |= rb_[5];                \
      rem[6] |= rb_[6]; rem[7] |= rb_[7];                                  \
    }                                                                      \
    ko[(cc)*64 + lane] = (float)((km >> lane) & 1ull);                     \
  }

__global__ __launch_bounds__(256) void k_nms(const u64* __restrict__ sup,
                                             const u64* __restrict__ validw,
                                             float* __restrict__ keep_out) {
  int b = blockIdx.x;
  __shared__ __align__(16) u64 lsn[K_SEL * 8];
  __shared__ u64 vsh[8];
  const u64* sb = sup + (size_t)b * K_SEL * 8;
  {
    const ulonglong2* s2 = (const ulonglong2*)sb;
    ulonglong2* l2 = (ulonglong2*)lsn;
    for (int k = threadIdx.x; k < K_SEL * 4; k += 256) l2[k] = s2[k];
  }
  if (threadIdx.x < 8) vsh[threadIdx.x] = validw[b * 8 + threadIdx.x];
  __syncthreads();
  if (threadIdx.x >= 64) return;
  int lane = threadIdx.x;
  u64 rem[8] = {0, 0, 0, 0, 0, 0, 0, 0};
  float* ko = keep_out + b * K_SEL;
  NCHUNK(0)
  NCHUNK(1)
  NCHUNK(2)
  NCHUNK(3)
  NCHUNK(4)
  NCHUNK(5)
  NCHUNK(6)
  NCHUNK(7)
}

extern "C" void kernel_launch(void* const* d_in, const int* in_sizes, int n_in,
                              void* d_out, int out_size, void* d_ws,
                              size_t ws_size, hipStream_t stream) {
  const float* logits = (const float*)d_in[0];
  const float* deltas = (const float*)d_in[1];
  const float* anchors = (const float*)d_in[2];
  float* out = (float*)d_out;
  int N = in_sizes[2] / 5;
  int B = in_sizes[1] / (N * 5);
  int C = (int)((long long)in_sizes[0] / ((long long)B * N));
  int BK = B * K_SEL;

  char* ws = (char*)d_ws;
  // zeroed region (contiguous): cnt, done3 (128B/img each), validw, sup
  size_t o_cnt = 0;                               // 512 B
  size_t o_done3 = o_cnt + 512;                   // 512 B
  size_t o_vw = o_done3 + 512;                    // 256 B
  size_t o_sup = o_vw + 256;                      // 128 KB
  size_t zero_end = o_sup + (size_t)B * K_SEL * 8 * 8;
  size_t o_cut = (zero_end + 255) & ~(size_t)255;
  size_t o_skey = (o_cut + 256 + 255) & ~(size_t)255;
  size_t o_cand = (o_skey + (size_t)B * N * 4 + 255) & ~(size_t)255;
  size_t o_corn = (o_cand + (size_t)B * CAP * 8 + 255) & ~(size_t)255;
  size_t o_meta = (o_corn + (size_t)BK * 8 * 4 + 255) & ~(size_t)255;
  size_t o_hp = (o_meta + (size_t)BK * 16 + 255) & ~(size_t)255;
  size_t o_hred = (o_hp + (size_t)B * SLABS * NBINS * 4 + 255) & ~(size_t)255;

  u32* cnt = (u32*)(ws + o_cnt);
  u32* done3 = (u32*)(ws + o_done3);
  u64* validw = (u64*)(ws + o_vw);
  u64* sup = (u64*)(ws + o_sup);
  u32* cutT = (u32*)(ws + o_cut);
  u32* skey = (u32*)(ws + o_skey);
  u64* cand = (u64*)(ws + o_cand);
  float* corners = (float*)(ws + o_corn);
  float4* meta = (float4*)(ws + o_meta);
  u32* histp = (u32*)(ws + o_hp);
  u32* hred = (u32*)(ws + o_hred);

  int nz4 = (int)(zero_end >> 4);

  int nb = (N + 255) / 256;
  k_maxhist<<<B * SLABS, 256, 0, stream>>>(logits, skey, histp, (float4*)ws,
                                           nz4, N);
  k_slabredcut<<<B * (NBINS / 256), 256, 0, stream>>>(histp, hred, done3,
                                                      cutT);
  k_compact<<<dim3(nb, B), 256, 0, stream>>>(skey, cutT, cand, cnt, N);
  int off_scores = BK * 5, off_labels = BK * 6, off_keep = BK * 7;
  k_rankdecode<<<dim3(CAP / 256, B), 256, 0, stream>>>(
      cand, cnt, logits, deltas, anchors, out, corners, meta, validw, N, C,
      off_scores, off_labels);
  k_pairclip<<<B * 128, 256, 0, stream>>>(meta, corners, sup);
  k_nms<<<B, 256, 0, stream>>>(sup, validw, out + off_keep);
}

// Round 17
// 121.033 us; speedup vs baseline: 5.5706x; 1.0353x over previous
//
#include <hip/hip_runtime.h>
#include <hip/hip_bf16.h>
#include <stdint.h>

typedef unsigned int u32;
typedef unsigned long long u64;

#define K_SEL 512
#define NBINS 4096
#define CAP 8192
#define SCORE_THR 0.05f
#define NMS_THR 0.5f
#define RPB 3072      // rows per k_maxhist block (mult of 256)
#define SLABS 128     // k_maxhist blocks per image

__device__ __forceinline__ u32 fkey(float x) {
  u32 u = __float_as_uint(x);
  return u ^ ((u32)((int)u >> 31) | 0x80000000u);
}
__device__ __forceinline__ float fkey_inv(u32 k) {
  u32 u = (k & 0x80000000u) ? (k ^ 0x80000000u) : ~k;
  return __uint_as_float(u);
}

// K1: fused per-anchor max + histogram. Coalesced float4 LDS staging,
// per-row max from LDS (stride-15 coprime 32 -> bank-free), LDS hist,
// one NON-ATOMIC flush per block into a private slab. Piggybacks zeroing.
__global__ __launch_bounds__(256) void k_maxhist(
    const float* __restrict__ logits, u32* __restrict__ skey,
    u32* __restrict__ histp, float4* __restrict__ zbuf, int nz4, int N) {
  int blk = blockIdx.x;
  int b = blk >> 7;          // SLABS == 128
  int lb = blk & (SLABS - 1);
  for (int i = blk * 256 + threadIdx.x; i < nz4; i += gridDim.x * 256)
    zbuf[i] = make_float4(0.f, 0.f, 0.f, 0.f);
  __shared__ __align__(16) float tile[256 * 15];
  __shared__ u32 sh[NBINS];
  for (int i = threadIdx.x; i < NBINS; i += 256) sh[i] = 0;
  int r0 = lb * RPB;
  for (int c = 0; c < RPB / 256; c++) {
    int n0 = r0 + c * 256;
    if (n0 >= N) break;
    int nrow = min(256, N - n0);
    const float* src = logits + ((size_t)b * N + n0) * 15;
    int tot = nrow * 15;
    if (((tot & 3) == 0) && ((((size_t)src) & 15) == 0)) {
      const float4* s4 = (const float4*)src;
      float4* t4 = (float4*)tile;
      int n4 = tot >> 2;
      for (int i = threadIdx.x; i < n4; i += 256) t4[i] = s4[i];
    } else {
      for (int i = threadIdx.x; i < tot; i += 256) tile[i] = src[i];
    }
    __syncthreads();
    if (threadIdx.x < nrow) {
      const float* row = tile + threadIdx.x * 15;
      float mv = row[0];
      for (int cc = 1; cc < 15; cc++) mv = fmaxf(mv, row[cc]);
      u32 key = fkey(mv);
      skey[(size_t)b * N + n0 + threadIdx.x] = key;
      atomicAdd(&sh[key >> 20], 1u);
    }
    __syncthreads();
  }
  u32* hp = histp + (size_t)blk * NBINS;
  for (int i = threadIdx.x; i < NBINS; i += 256) hp[i] = sh[i];
}

// K1b: WIDE slab reduction: hred[b][bin] = sum over 128 slabs.
// Consecutive threads read consecutive bins -> fully coalesced; 8MB total.
__global__ __launch_bounds__(256) void k_slabred(const u32* __restrict__ histp,
                                                 u32* __restrict__ hred) {
  int b = blockIdx.y;
  int bin = blockIdx.x * 256 + threadIdx.x;  // gridDim.x = NBINS/256
  const u32* base = histp + (size_t)b * SLABS * NBINS + bin;
  u32 s = 0;
#pragma unroll 8
  for (int sl = 0; sl < SLABS; sl++) s += base[(size_t)sl * NBINS];
  hred[b * NBINS + bin] = s;
}

// K2: cutoff bin T = max{bin : suffix_count(bin) >= K_SEL} from reduced hist.
__global__ __launch_bounds__(256) void k_cutoff(const u32* __restrict__ hred,
                                                u32* __restrict__ cutT) {
  int b = blockIdx.x;
  int t = threadIdx.x;
  const u32* hb = hred + b * NBINS;
  u32 h[16];
  u32 s = 0;
#pragma unroll
  for (int i = 0; i < 16; i++) {
    h[i] = hb[t * 16 + i];
    s += h[i];
  }
  __shared__ u32 cs[256];
  cs[t] = s;
  __syncthreads();
  for (int off = 1; off < 256; off <<= 1) {
    u32 add = (t + off < 256) ? cs[t + off] : 0;
    __syncthreads();
    cs[t] += add;
    __syncthreads();
  }
  u32 run = (t < 255) ? cs[t + 1] : 0;
  for (int i = 15; i >= 0; i--) {
    u32 sfx = run + h[i];
    if (run < (u32)K_SEL && sfx >= (u32)K_SEL) cutT[b] = (u32)(t * 16 + i);
    run = sfx;
  }
}

// K3: compact candidates with bin >= cutT; LDS-aggregated block atomic;
// per-image counters padded to 128B.
__global__ __launch_bounds__(256) void k_compact(
    const u32* __restrict__ skey, const u32* __restrict__ cutT,
    u64* __restrict__ cand, u32* __restrict__ cnt, int N) {
  int b = blockIdx.y;
  int n = blockIdx.x * 256 + threadIdx.x;
  __shared__ u32 lcnt, lbase;
  if (threadIdx.x == 0) lcnt = 0;
  __syncthreads();
  u32 key = 0;
  bool ok = false;
  u32 lpos = 0;
  if (n < N) {
    key = skey[(size_t)b * N + n];
    ok = (key >> 20) >= cutT[b];
  }
  if (ok) lpos = atomicAdd(&lcnt, 1u);
  __syncthreads();
  if (threadIdx.x == 0 && lcnt) lbase = atomicAdd(&cnt[b * 32], lcnt);
  __syncthreads();
  if (ok) {
    u32 pos = lbase + lpos;
    if (pos < CAP)
      cand[(size_t)b * CAP + pos] = ((u64)key << 32) | (u32)(~(u32)n);
  }
}

// K4: rank by counting (keys unique), decode, emit packed meta float4.
__global__ __launch_bounds__(256) void k_rankdecode(
    const u64* __restrict__ cand, const u32* __restrict__ cnt,
    const float* __restrict__ logits, const float* __restrict__ deltas,
    const float* __restrict__ anchors, float* __restrict__ out,
    float* __restrict__ corners, float4* __restrict__ meta,
    u64* __restrict__ validw, int N, int C, int off_scores, int off_labels) {
  int b = blockIdx.y;
  int M = (int)min(cnt[b * 32], (u32)CAP);
  if (blockIdx.x * 256 >= (u32)M) return;
  int m = blockIdx.x * 256 + threadIdx.x;
  u64 my = (m < M) ? cand[(size_t)b * CAP + m] : 0ull;
  int rank = 0;
  __shared__ u64 t[256];
  for (int j0 = 0; j0 < M; j0 += 256) {
    int j = j0 + threadIdx.x;
    t[threadIdx.x] = (j < M) ? cand[(size_t)b * CAP + j] : 0ull;
    __syncthreads();
    int lim = min(256, M - j0);
    for (int jj = 0; jj < lim; jj++) rank += (t[jj] > my) ? 1 : 0;
    __syncthreads();
  }
  if (m >= M || rank >= K_SEL) return;
  int g = b * K_SEL + rank;
  u32 key = (u32)(my >> 32);
  int idx = (int)(~(u32)my);
  float ml = fkey_inv(key);
  float score = 1.0f / (1.0f + expf(-ml));
  const float* lr = logits + ((size_t)b * N + idx) * C;
  float bv = lr[0];
  int lab = 0;
  for (int c = 1; c < C; c++) {
    float v = lr[c];
    if (v > bv) { bv = v; lab = c; }
  }
  const float* ar = anchors + (size_t)idx * 5;
  const float* dr = deltas + ((size_t)b * N + idx) * 5;
  float ax = ar[0], ay = ar[1], aw = ar[2], ah = ar[3], aa = ar[4];
  float dx = dr[0], dy = dr[1], dwv = dr[2], dhv = dr[3], da = dr[4];
  float px = ax + dx * aw;
  float py = ay + dy * ah;
  float pw = aw * expf(fminf(fmaxf(dwv, -4.0f), 4.0f));
  float ph = ah * expf(fminf(fmaxf(dhv, -4.0f), 4.0f));
  float pa = aa + da * 57.295779513082323f;
  float* ob = out + (size_t)g * 5;
  ob[0] = px; ob[1] = py; ob[2] = pw; ob[3] = ph; ob[4] = pa;
  out[off_scores + g] = score;
  out[off_labels + g] = (float)lab;
  if (score > SCORE_THR) atomicOr(&validw[g >> 6], 1ull << (g & 63));
  float tt = pa * 0.017453292519943295f;
  float cc = cosf(tt), sn = sinf(tt);
  float hx = pw * 0.5f, hy = ph * 0.5f;
  float* cp = corners + (size_t)g * 8;
  cp[0] = px + cc * (-hx) - sn * (-hy);
  cp[1] = py + sn * (-hx) + cc * (-hy);
  cp[2] = px + cc * (hx) - sn * (-hy);
  cp[3] = py + sn * (hx) + cc * (-hy);
  cp[4] = px + cc * (hx) - sn * (hy);
  cp[5] = py + sn * (hx) + cc * (hy);
  cp[6] = px + cc * (-hx) - sn * (hy);
  cp[7] = py + sn * (-hx) + cc * (hy);
  meta[g] = make_float4(px, py, 0.5f * sqrtf(pw * pw + ph * ph), pw * ph);
}

// K5: fused prefilter + exact clip. One wave per i-row (i wave-uniform),
// lane l covers j = l + 64k -> SoA LDS reads are bank-conflict-free.
__global__ __launch_bounds__(256) void k_pairclip(
    const float4* __restrict__ meta, const float* __restrict__ corners,
    u64* __restrict__ sup) {
  int b = blockIdx.x >> 7;          // 128 blocks per image
  int i0 = (blockIdx.x & 127) * 4;  // 4 i-rows per block (one per wave)
  __shared__ float js_x[K_SEL], js_y[K_SEL], js_r[K_SEL], js_a[K_SEL];
  __shared__ u32 list[2048];
  __shared__ u32 lcnt;
  if (threadIdx.x == 0) lcnt = 0;
  for (int t = threadIdx.x; t < K_SEL; t += 256) {
    float4 mj = meta[b * K_SEL + t];
    js_x[t] = mj.x; js_y[t] = mj.y; js_r[t] = mj.z; js_a[t] = mj.w;
  }
  __syncthreads();
  int i = i0 + (threadIdx.x >> 6);
  int lane = threadIdx.x & 63;
  float4 mi = meta[b * K_SEL + i];  // uniform per wave -> broadcast
  float cxi = mi.x, cyi = mi.y, ri = mi.z, ai = mi.w;
#pragma unroll
  for (int k = 0; k < 8; k++) {
    int j = lane + 64 * k;
    if (j <= i) continue;
    float ddx = cxi - js_x[j], ddy = cyi - js_y[j];
    float rr = ri + js_r[j];
    float d2 = ddx * ddx + ddy * ddy;
    if (d2 > rr * rr * 1.0001f) continue;
    float aj = js_a[j];
    float mnA = fminf(ai, aj), mxA = fmaxf(ai, aj);
    if (2.0f * mnA < 0.999f * mxA) continue;
    u32 p = atomicAdd(&lcnt, 1u);
    list[p] = ((u32)i << 9) | (u32)j;
  }
  __syncthreads();
  u32 M = lcnt;
  for (u32 l = threadIdx.x; l < M; l += 256) {
    u32 pk = list[l];
    int i2 = (int)(pk >> 9);
    int j2 = (int)(pk & 511u);
    int gi2 = b * K_SEL + i2, gj2 = b * K_SEL + j2;
    const float* ci = corners + (size_t)gi2 * 8;
    const float* cj = corners + (size_t)gj2 * 8;
    float X[8], Y[8], bx[4], by[4];
#pragma unroll
    for (int m = 0; m < 4; m++) {
      X[m] = ci[2 * m]; Y[m] = ci[2 * m + 1];
      X[m + 4] = 0.f; Y[m + 4] = 0.f;
      bx[m] = cj[2 * m]; by[m] = cj[2 * m + 1];
    }
    int cnt = 4;
#pragma unroll
    for (int e = 0; e < 4; e++) {
      float axp = bx[e], ayp = by[e];
      float ex = bx[(e + 1) & 3] - axp, ey = by[(e + 1) & 3] - ayp;
      float d[8];
#pragma unroll
      for (int m = 0; m < 8; m++)
        d[m] = ex * (Y[m] - ayp) - ey * (X[m] - axp);
      float NX[8], NY[8];
#pragma unroll
      for (int s = 0; s < 8; s++) { NX[s] = 0.f; NY[s] = 0.f; }
      int oc = 0;
#pragma unroll
      for (int m = 0; m < 8; m++) {
        bool act = (m < cnt);
        bool isLast = (m + 1 == cnt);
        float dn = isLast ? d[0] : d[(m + 1) & 7];
        float xn = isLast ? X[0] : X[(m + 1) & 7];
        float yn = isLast ? Y[0] : Y[(m + 1) & 7];
        bool cin = (d[m] >= 0.f), nin = (dn >= 0.f);
        bool e1 = act && cin;
        bool e2 = act && (cin != nin);
#pragma unroll
        for (int s = 0; s < 8; s++) {
          bool w = e1 && (oc == s);
          NX[s] = w ? X[m] : NX[s];
          NY[s] = w ? Y[m] : NY[s];
        }
        oc += e1 ? 1 : 0;
        float den = d[m] - dn;
        float dd = (fabsf(den) < 1e-9f) ? 1e-9f : den;
        float tt = d[m] / dd;
        float ix = X[m] + tt * (xn - X[m]);
        float iy = Y[m] + tt * (yn - Y[m]);
#pragma unroll
        for (int s = 0; s < 8; s++) {
          bool w = e2 && (oc == s);
          NX[s] = w ? ix : NX[s];
          NY[s] = w ? iy : NY[s];
        }
        oc += e2 ? 1 : 0;
      }
      cnt = oc;
#pragma unroll
      for (int m = 0; m < 8; m++) { X[m] = NX[m]; Y[m] = NY[m]; }
    }
    float sum = 0.f;
#pragma unroll
    for (int m = 0; m < 8; m++) {
      bool act = (m < cnt);
      bool isLast = (m + 1 == cnt);
      float xn = isLast ? X[0] : X[(m + 1) & 7];
      float yn = isLast ? Y[0] : Y[(m + 1) & 7];
      float cr = X[m] * yn - Y[m] * xn;
      sum += act ? cr : 0.f;
    }
    float inter = (cnt >= 3) ? 0.5f * fabsf(sum) : 0.f;
    float ai2 = js_a[i2], aj2 = js_a[j2];
    float uni = ai2 + aj2 - inter;
    float iou = inter / fmaxf(uni, 1e-6f);
    if (iou > NMS_THR)
      atomicOr(&sup[((size_t)b * K_SEL + i2) * 8 + (j2 >> 6)],
               1ull << (j2 & 63));
  }
}

// K6: sequential NMS sweep — single-word chain + catch-up ORs for kept boxes.
#define NSTEP(PB, S, cc)                                                   \
  {                                                                        \
    u64 live_ = ((vv >> (S)) & ~(rw >> (S))) & 1ull;                       \
    u64 m_ = (u64)0 - live_;                                               \
    rw |= PB & m_;                                                         \
    km |= live_ << (S);                                                    \
    if ((S) < 48) PB = lsn[((cc)*64 + (S) + 16) * 8 + (cc)];               \
  }

#define NGROUP16(S0, cc)                                                   \
  NSTEP(P0, (S0) + 0, cc) NSTEP(P1, (S0) + 1, cc)                          \
  NSTEP(P2, (S0) + 2, cc) NSTEP(P3, (S0) + 3, cc)                          \
  NSTEP(P4, (S0) + 4, cc) NSTEP(P5, (S0) + 5, cc)                          \
  NSTEP(P6, (S0) + 6, cc) NSTEP(P7, (S0) + 7, cc)                          \
  NSTEP(P8, (S0) + 8, cc) NSTEP(P9, (S0) + 9, cc)                          \
  NSTEP(P10, (S0) + 10, cc) NSTEP(P11, (S0) + 11, cc)                      \
  NSTEP(P12, (S0) + 12, cc) NSTEP(P13, (S0) + 13, cc)                      \
  NSTEP(P14, (S0) + 14, cc) NSTEP(P15, (S0) + 15, cc)

#define NCHUNK(cc)                                                         \
  {                                                                        \
    u64 vv = vsh[cc];                                                      \
    u64 rw = rem[cc];                                                      \
    u64 km = 0;                                                            \
    u64 P0 = lsn[((cc)*64 + 0) * 8 + (cc)];                                \
    u64 P1 = lsn[((cc)*64 + 1) * 8 + (cc)];                                \
    u64 P2 = lsn[((cc)*64 + 2) * 8 + (cc)];                                \
    u64 P3 = lsn[((cc)*64 + 3) * 8 + (cc)];                                \
    u64 P4 = lsn[((cc)*64 + 4) * 8 + (cc)];                                \
    u64 P5 = lsn[((cc)*64 + 5) * 8 + (cc)];                                \
    u64 P6 = lsn[((cc)*64 + 6) * 8 + (cc)];                                \
    u64 P7 = lsn[((cc)*64 + 7) * 8 + (cc)];                                \
    u64 P8 = lsn[((cc)*64 + 8) * 8 + (cc)];                                \
    u64 P9 = lsn[((cc)*64 + 9) * 8 + (cc)];                                \
    u64 P10 = lsn[((cc)*64 + 10) * 8 + (cc)];                              \
    u64 P11 = lsn[((cc)*64 + 11) * 8 + (cc)];                              \
    u64 P12 = lsn[((cc)*64 + 12) * 8 + (cc)];                              \
    u64 P13 = lsn[((cc)*64 + 13) * 8 + (cc)];                              \
    u64 P14 = lsn[((cc)*64 + 14) * 8 + (cc)];                              \
    u64 P15 = lsn[((cc)*64 + 15) * 8 + (cc)];                              \
    NGROUP16(0, cc) NGROUP16(16, cc) NGROUP16(32, cc) NGROUP16(48, cc)     \
    u64 kk = km;                                                           \
    while (kk) {                                                           \
      int r_ = (cc)*64 + __builtin_ctzll(kk);                              \
      kk &= kk - 1ull;                                                     \
      const u64* rb_ = lsn + r_ * 8;                                       \
      rem[0] |= rb_[0]; rem[1] |= rb_[1]; rem[2] |= rb_[2];                \
      rem[3] |= rb_[3]; rem[4] |= rb_[4]; rem[5] |= rb_[5];                \
      rem[6] |= rb_[6]; rem[7] |= rb_[7];                                  \
    }                                                                      \
    ko[(cc)*64 + lane] = (float)((km >> lane) & 1ull);                     \
  }

__global__ __launch_bounds__(256) void k_nms(const u64* __restrict__ sup,
                                             const u64* __restrict__ validw,
                                             float* __restrict__ keep_out) {
  int b = blockIdx.x;
  __shared__ __align__(16) u64 lsn[K_SEL * 8];
  __shared__ u64 vsh[8];
  const u64* sb = sup + (size_t)b * K_SEL * 8;
  {
    const ulonglong2* s2 = (const ulonglong2*)sb;
    ulonglong2* l2 = (ulonglong2*)lsn;
    for (int k = threadIdx.x; k < K_SEL * 4; k += 256) l2[k] = s2[k];
  }
  if (threadIdx.x < 8) vsh[threadIdx.x] = validw[b * 8 + threadIdx.x];
  __syncthreads();
  if (threadIdx.x >= 64) return;
  int lane = threadIdx.x;
  u64 rem[8] = {0, 0, 0, 0, 0, 0, 0, 0};
  float* ko = keep_out + b * K_SEL;
  NCHUNK(0)
  NCHUNK(1)
  NCHUNK(2)
  NCHUNK(3)
  NCHUNK(4)
  NCHUNK(5)
  NCHUNK(6)
  NCHUNK(7)
}

extern "C" void kernel_launch(void* const* d_in, const int* in_sizes, int n_in,
                              void* d_out, int out_size, void* d_ws,
                              size_t ws_size, hipStream_t stream) {
  const float* logits = (const float*)d_in[0];
  const float* deltas = (const float*)d_in[1];
  const float* anchors = (const float*)d_in[2];
  float* out = (float*)d_out;
  int N = in_sizes[2] / 5;
  int B = in_sizes[1] / (N * 5);
  int C = (int)((long long)in_sizes[0] / ((long long)B * N));
  int BK = B * K_SEL;

  char* ws = (char*)d_ws;
  // zeroed region (contiguous): cnt(128B/img), validw, sup
  size_t o_cnt = 0;                               // 512 B
  size_t o_vw = o_cnt + 512;                      // 256 B
  size_t o_sup = o_vw + 256;                      // 128 KB
  size_t zero_end = o_sup + (size_t)B * K_SEL * 8 * 8;
  size_t o_cut = (zero_end + 255) & ~(size_t)255;
  size_t o_skey = (o_cut + 256 + 255) & ~(size_t)255;
  size_t o_cand = (o_skey + (size_t)B * N * 4 + 255) & ~(size_t)255;
  size_t o_corn = (o_cand + (size_t)B * CAP * 8 + 255) & ~(size_t)255;
  size_t o_meta = (o_corn + (size_t)BK * 8 * 4 + 255) & ~(size_t)255;
  size_t o_hp = (o_meta + (size_t)BK * 16 + 255) & ~(size_t)255;
  size_t o_hred = (o_hp + (size_t)B * SLABS * NBINS * 4 + 255) & ~(size_t)255;

  u32* cnt = (u32*)(ws + o_cnt);
  u64* validw = (u64*)(ws + o_vw);
  u64* sup = (u64*)(ws + o_sup);
  u32* cutT = (u32*)(ws + o_cut);
  u32* skey = (u32*)(ws + o_skey);
  u64* cand = (u64*)(ws + o_cand);
  float* corners = (float*)(ws + o_corn);
  float4* meta = (float4*)(ws + o_meta);
  u32* histp = (u32*)(ws + o_hp);   // B*SLABS*NBINS*4 = 8 MB
  u32* hred = (u32*)(ws + o_hred);  // B*NBINS*4 = 64 KB

  int nz4 = (int)(zero_end >> 4);

  int nb = (N + 255) / 256;
  k_maxhist<<<B * SLABS, 256, 0, stream>>>(logits, skey, histp, (float4*)ws,
                                           nz4, N);
  k_slabred<<<dim3(NBINS / 256, B), 256, 0, stream>>>(histp, hred);
  k_cutoff<<<B, 256, 0, stream>>>(hred, cutT);
  k_compact<<<dim3(nb, B), 256, 0, stream>>>(skey, cutT, cand, cnt, N);
  int off_scores = BK * 5, off_labels = BK * 6, off_keep = BK * 7;
  k_rankdecode<<<dim3(CAP / 256, B), 256, 0, stream>>>(
      cand, cnt, logits, deltas, anchors, out, corners, meta, validw, N, C,
      off_scores, off_labels);
  k_pairclip<<<B * 128, 256, 0, stream>>>(meta, corners, sup);
  k_nms<<<B, 256, 0, stream>>>(sup, validw, out + off_keep);
}